// Round 6
// baseline (450.680 us; speedup 1.0000x reference)
//
#include <hip/hip_runtime.h>

#define N_IMG 9216
#define DFEAT 1024
#define NBR 72           // 128-row panels
#define NPAIR 1332       // sum over bcol<36 of min(72, 2*bcol+2)
#define NMLP 144         // 64-row MLP blocks

typedef __attribute__((ext_vector_type(8))) short short8;
typedef __attribute__((ext_vector_type(4))) float floatx4;
typedef __attribute__((ext_vector_type(16))) float floatx16;
typedef __attribute__((ext_vector_type(4))) int intx4;
typedef __attribute__((ext_vector_type(8))) int intx8;

// exp2-folded constants: sim = exp2(delta - gamma * rcp(1+u))
//   delta_ij = Pi*Pj          (P = sqrt(s) * C2, C2 = sqrt(2*log2e/1024))
//   gamma_ij = s~i + s~j + delta_ij   (s~ = s * C1, C1 = log2e/1024)
#define C1F 0.0014088818759657845f
#define C2F 0.05308355472172724f

__device__ __forceinline__ void async_copy16(const void* g, void* l) {
  __builtin_amdgcn_global_load_lds((const __attribute__((address_space(1))) void*)g,
                                   (__attribute__((address_space(3))) void*)l,
                                   16, 0, 0);
}

__device__ __forceinline__ unsigned short f2bf(float x) {
  union { float f; unsigned u; } a; a.f = x;
  unsigned u = a.u;
  u += 0x7fffu + ((u >> 16) & 1u);   // round-to-nearest-even
  return (unsigned short)(u >> 16);
}

// ---- conflict-free LDS swizzle (64 B rows, 2 rows per 128-B line) ----
// line L = r>>1; row parity rp owns granules 2*((c+L)&3)+rp.
// staging source decode: phys chunk P -> (row, chunk c)
__device__ __forceinline__ size_t sw_src(int P) {
  int L = P >> 3, s = P & 7;
  int row = 2 * L + (s & 1);
  int c = ((s >> 1) - L) & 3;
  return (size_t)row * DFEAT + (size_t)c * 16;
}
__device__ __forceinline__ intx4 ld16s(const unsigned char* base, int r, int c) {
  int L = r >> 1;
  int slot = (((c + L) & 3) << 1) | (r & 1);
  return *(const intx4*)(base + L * 128 + slot * 16);
}
__device__ __forceinline__ intx8 ldfrags(const unsigned char* base, int r, int kh) {
  intx4 lo = ld16s(base, r, kh * 2);
  intx4 hi = ld16s(base, r, kh * 2 + 1);
  intx8 v;
  v[0] = lo[0]; v[1] = lo[1]; v[2] = lo[2]; v[3] = lo[3];
  v[4] = hi[0]; v[5] = hi[1]; v[6] = hi[2]; v[7] = hi[3];
  return v;
}

// ---- kernel 1: fp32 -> NORMALIZED fp8(e4m3) rows + s~/P; also W1^T bf16; init sums ----
__global__ __launch_bounds__(256) void convert_prep(const float* __restrict__ f,
                                                    const float* __restrict__ W1,
                                                    unsigned char* __restrict__ fb8,
                                                    float* __restrict__ sL,
                                                    float* __restrict__ pL,
                                                    unsigned short* __restrict__ W1t,
                                                    double* __restrict__ sums) {
  int b = blockIdx.x, t = threadIdx.x;
  if (b < 2304) {
    int lane = t & 63, wave = t >> 6;
    int row = b * 4 + wave;                      // one wave per row
    const float4* src = (const float4*)f + (size_t)row * 256;
    unsigned int* dst = (unsigned int*)(fb8 + (size_t)row * DFEAT);
    float4 v0 = src[lane], v1 = src[64 + lane], v2 = src[128 + lane], v3 = src[192 + lane];
    float s = v0.x * v0.x + v0.y * v0.y + v0.z * v0.z + v0.w * v0.w
            + v1.x * v1.x + v1.y * v1.y + v1.z * v1.z + v1.w * v1.w
            + v2.x * v2.x + v2.y * v2.y + v2.z * v2.z + v2.w * v2.w
            + v3.x * v3.x + v3.y * v3.y + v3.z * v3.z + v3.w * v3.w;
#pragma unroll
    for (int off = 32; off > 0; off >>= 1) s += __shfl_xor(s, off, 64);
    float rinv = rsqrtf(s);
    float4 vv[4] = {v0, v1, v2, v3};
#pragma unroll
    for (int j = 0; j < 4; j++) {
      float4 v = vv[j];
      int pk = __builtin_amdgcn_cvt_pk_fp8_f32(v.x * rinv, v.y * rinv, 0, false);
      pk = __builtin_amdgcn_cvt_pk_fp8_f32(v.z * rinv, v.w * rinv, pk, true);
      dst[j * 64 + lane] = (unsigned int)pk;
    }
    if (lane == 0) {
      sL[row] = s * C1F;
      pL[row] = sqrtf(s) * C2F;
    }
  } else {
    int j = b - 2304;                            // W1 column j -> W1t row j
    if (j == 0 && t < 2) sums[t] = 0.0;
    for (int k = t; k < DFEAT; k += 256)
      W1t[(size_t)j * DFEAT + k] = f2bf(W1[(size_t)k * 128 + j]);
  }
}

// ---- kernel 2 (fused): blocks [0,NMLP) = MLP; [NMLP, NMLP+NPAIR) = gram ----
__global__ __launch_bounds__(256, 2) void gram_mlp(
    const unsigned char* __restrict__ fb8,
    const float* __restrict__ sL, const float* __restrict__ pL,
    const float* __restrict__ f, const unsigned short* __restrict__ W1t,
    const float* __restrict__ scores, const float* __restrict__ W1,
    const float* __restrict__ b1, const float* __restrict__ g1,
    const float* __restrict__ be1,
    const float* __restrict__ W2, const float* __restrict__ b2,
    const float* __restrict__ g2, const float* __restrict__ be2,
    const float* __restrict__ W3, const float* __restrict__ b3,
    double* __restrict__ sums) {
  __shared__ union __align__(16) SMem {
    struct {
      unsigned char Ab[2][8192];    // 128 rows x 64 B, swizzled
      unsigned char Bb[2][16384];   // 256 rows x 64 B, swizzled
      float sA[128], pA[128], sB[256], pB[256];
      float wpart[4];
    } g;
    struct {
      float As32[64 * 32];
      unsigned short Bs[128 * 32];
      float h1s[64][128];
      float h2s[64][65];
      float sc[64], b1s[128], g1s[128], be1s[128], wls[128], ls[64];
    } m;
  } sm;

  int t = threadIdx.x, lane = t & 63, wave = t >> 6;

  if (blockIdx.x >= NMLP) {
    // ================= GRAM PATH =================
    int rem = blockIdx.x - NMLP, bcol = 0;
    for (;;) {
      int mlim = 2 * bcol + 2; if (mlim > NBR) mlim = NBR;
      if (rem < mlim) break;
      rem -= mlim; bcol++;
    }
    int brow = rem;

    if (t < 128) { sm.g.sA[t] = sL[brow * 128 + t]; sm.g.pA[t] = pL[brow * 128 + t]; }
    sm.g.sB[t] = sL[bcol * 256 + t];
    sm.g.pB[t] = pL[bcol * 256 + t];

    const unsigned char* Asrc = fb8 + (size_t)brow * 128 * DFEAT;
    const unsigned char* Bsrc = fb8 + (size_t)bcol * 256 * DFEAT;

    const size_t d0 = sw_src(t);
    const size_t d1 = sw_src(t + 256);
    const size_t d2 = sw_src(t + 512);
    const size_t d3 = sw_src(t + 768);

    floatx16 acc[2][4];
#pragma unroll
    for (int mi = 0; mi < 2; mi++)
#pragma unroll
      for (int ni = 0; ni < 4; ni++)
#pragma unroll
        for (int e = 0; e < 16; e++) acc[mi][ni][e] = 0.f;

    const int wr = (wave & 1) * 64, wc = (wave >> 1) * 128;
    const int r32 = lane & 31, kh = lane >> 5;

    // prologue: stage kb=0 into buffer 0
    async_copy16(Asrc + d0, &sm.g.Ab[0][t * 16]);
    async_copy16(Asrc + d1, &sm.g.Ab[0][(t + 256) * 16]);
    async_copy16(Bsrc + d0, &sm.g.Bb[0][t * 16]);
    async_copy16(Bsrc + d1, &sm.g.Bb[0][(t + 256) * 16]);
    async_copy16(Bsrc + d2, &sm.g.Bb[0][(t + 512) * 16]);
    async_copy16(Bsrc + d3, &sm.g.Bb[0][(t + 768) * 16]);

    for (int kb = 0; kb < 16; kb++) {
      __syncthreads();
      if (kb < 15) {
        const int nb = (kb + 1) & 1;
        const size_t k0 = (size_t)(kb + 1) * 64;
        async_copy16(Asrc + d0 + k0, &sm.g.Ab[nb][t * 16]);
        async_copy16(Asrc + d1 + k0, &sm.g.Ab[nb][(t + 256) * 16]);
        async_copy16(Bsrc + d0 + k0, &sm.g.Bb[nb][t * 16]);
        async_copy16(Bsrc + d1 + k0, &sm.g.Bb[nb][(t + 256) * 16]);
        async_copy16(Bsrc + d2 + k0, &sm.g.Bb[nb][(t + 512) * 16]);
        async_copy16(Bsrc + d3 + k0, &sm.g.Bb[nb][(t + 768) * 16]);
      }
      const unsigned char* Ac = sm.g.Ab[kb & 1];
      const unsigned char* Bc = sm.g.Bb[kb & 1];
      intx8 a[2], b[4];
#pragma unroll
      for (int mi = 0; mi < 2; mi++) a[mi] = ldfrags(Ac, wr + mi * 32 + r32, kh);
#pragma unroll
      for (int ni = 0; ni < 4; ni++) b[ni] = ldfrags(Bc, wc + ni * 32 + r32, kh);
#pragma unroll
      for (int mi = 0; mi < 2; mi++)
#pragma unroll
        for (int ni = 0; ni < 4; ni++)
          acc[mi][ni] = __builtin_amdgcn_mfma_scale_f32_32x32x64_f8f6f4(
              a[mi], b[ni], acc[mi][ni], 0, 0, 0, 0x7F7F7F7F, 0, 0x7F7F7F7F);
    }

    // epilogue: u = cos directly. C/D layout col=lane&31, row=(reg&3)+8*(reg>>2)+4*kh
    const bool interior = (brow < 2 * bcol);
    float lsum = 0.f;
#pragma unroll
    for (int mi = 0; mi < 2; mi++) {
      const int rbase = wr + mi * 32 + 4 * kh;
      float si[16], pi[16];
#pragma unroll
      for (int reg = 0; reg < 16; reg++) {
        int i_loc = rbase + (reg & 3) + 8 * (reg >> 2);
        si[reg] = sm.g.sA[i_loc];
        pi[reg] = sm.g.pA[i_loc];
      }
#pragma unroll
      for (int ni = 0; ni < 4; ni++) {
        int j_loc = wc + ni * 32 + r32;
        float sj = sm.g.sB[j_loc], pj = sm.g.pB[j_loc];
        if (interior) {
#pragma unroll
          for (int reg = 0; reg < 16; reg++) {
            float u = acc[mi][ni][reg];
            float r = __builtin_amdgcn_rcpf(1.f + u);
            float del = pi[reg] * pj;
            float gam = si[reg] + sj + del;
            lsum += __builtin_amdgcn_exp2f(fmaf(-gam, r, del));
          }
        } else {
          int j_g = bcol * 256 + j_loc;
#pragma unroll
          for (int reg = 0; reg < 16; reg++) {
            int i_g = brow * 128 + rbase + (reg & 3) + 8 * (reg >> 2);
            float u = acc[mi][ni][reg];
            float r = __builtin_amdgcn_rcpf(1.f + u);
            float del = pi[reg] * pj;
            float gam = si[reg] + sj + del;
            float sim = __builtin_amdgcn_exp2f(fmaf(-gam, r, del));
            lsum += (i_g < j_g) ? 2.f * sim : (i_g == j_g ? 1.f : 0.f);
          }
        }
      }
    }
    if (interior) lsum *= 2.f;
#pragma unroll
    for (int off = 32; off > 0; off >>= 1) lsum += __shfl_down(lsum, off, 64);
    if (lane == 0) sm.g.wpart[wave] = lsum;
    __syncthreads();
    if (t == 0)
      atomicAdd(&sums[0],
                (double)(sm.g.wpart[0] + sm.g.wpart[1] + sm.g.wpart[2] + sm.g.wpart[3]));
    return;
  }

  // ================= MLP PATH (64 rows/block) =================
  int r0 = blockIdx.x * 64;
  if (t < 64) sm.m.sc[t] = scores[r0 + t];
  if (t < 128) {
    sm.m.b1s[t] = b1[t]; sm.m.g1s[t] = g1[t]; sm.m.be1s[t] = be1[t];
    sm.m.wls[t] = W1[(size_t)DFEAT * 128 + t];
  }

  floatx4 acc[2][4];
#pragma unroll
  for (int a = 0; a < 2; a++)
#pragma unroll
    for (int b = 0; b < 4; b++) acc[a][b] = (floatx4){0.f, 0.f, 0.f, 0.f};

  const int wr = (wave & 1) * 32, wc = (wave >> 1) * 64;

  for (int k0 = 0; k0 < DFEAT; k0 += 32) {
    __syncthreads();
    {
      // A: 512 chunks (64 rows x 8); phys chunk p of row r holds logical p^(r&7)
      int c = t, rA = c >> 3, p = c & 7, l = p ^ (rA & 7);
      async_copy16(f + (size_t)(r0 + rA) * DFEAT + k0 + l * 4, (char*)sm.m.As32 + c * 16);
      c = t + 256; rA = c >> 3; p = c & 7; l = p ^ (rA & 7);
      async_copy16(f + (size_t)(r0 + rA) * DFEAT + k0 + l * 4, (char*)sm.m.As32 + c * 16);
      // B: 512 chunks (128 rows x 4); phys p holds logical p^(r&3)
      c = t; int rB = c >> 2; p = c & 3; l = p ^ (rB & 3);
      async_copy16(W1t + (size_t)rB * DFEAT + k0 + l * 8, (char*)sm.m.Bs + c * 16);
      c = t + 256; rB = c >> 2; p = c & 3; l = p ^ (rB & 3);
      async_copy16(W1t + (size_t)rB * DFEAT + k0 + l * 8, (char*)sm.m.Bs + c * 16);
    }
    __syncthreads();

    const int mrow = lane & 15, kq = (lane >> 4) * 8;
    short8 a[2], b[4];
#pragma unroll
    for (int mt = 0; mt < 2; mt++) {
      int row = wr + mt * 16 + mrow;
      int l0 = kq >> 2;
      int p0 = l0 ^ (row & 7), p1 = (l0 + 1) ^ (row & 7);
      float4 f0 = *(const float4*)&sm.m.As32[row * 32 + p0 * 4];
      float4 f1 = *(const float4*)&sm.m.As32[row * 32 + p1 * 4];
      short8 af;
      af[0] = (short)f2bf(f0.x); af[1] = (short)f2bf(f0.y);
      af[2] = (short)f2bf(f0.z); af[3] = (short)f2bf(f0.w);
      af[4] = (short)f2bf(f1.x); af[5] = (short)f2bf(f1.y);
      af[6] = (short)f2bf(f1.z); af[7] = (short)f2bf(f1.w);
      a[mt] = af;
    }
#pragma unroll
    for (int nt = 0; nt < 4; nt++) {
      int row = wc + nt * 16 + mrow;
      int p = (kq >> 3) ^ (row & 3);
      b[nt] = *(const short8*)&sm.m.Bs[row * 32 + p * 8];
    }
#pragma unroll
    for (int mt = 0; mt < 2; mt++)
#pragma unroll
      for (int nt = 0; nt < 4; nt++)
        acc[mt][nt] = __builtin_amdgcn_mfma_f32_16x16x32_bf16(a[mt], b[nt], acc[mt][nt], 0, 0, 0);
  }

  const float inv = 1.0f / sqrtf(1.0f + 1e-5f);
  const int rq = (lane >> 4) * 4, cn = lane & 15;
#pragma unroll
  for (int nt = 0; nt < 4; nt++) {
    int j = wc + nt * 16 + cn;
    float bj = sm.m.b1s[j], gj = sm.m.g1s[j] * inv, bej = sm.m.be1s[j], wj = sm.m.wls[j];
#pragma unroll
    for (int mt = 0; mt < 2; mt++) {
#pragma unroll
      for (int rr = 0; rr < 4; rr++) {
        int iL = wr + mt * 16 + rq + rr;
        float pre = acc[mt][nt][rr] + sm.m.sc[iL] * wj + bj;
        sm.m.h1s[iL][j] = fmaxf(gj * pre + bej, 0.f);
      }
    }
  }
  __syncthreads();

  // layer 2: 128 -> 64. j = t&63, 16 rows/thread (broadcast LDS reads)
  {
    int j = t & 63, rg = (t >> 6) * 16;
    float a2[16];
#pragma unroll
    for (int rr = 0; rr < 16; rr++) a2[rr] = 0.f;
    for (int k = 0; k < 128; k++) {
      float w = W2[k * 64 + j];
#pragma unroll
      for (int rr = 0; rr < 16; rr++) a2[rr] = fmaf(sm.m.h1s[rg + rr][k], w, a2[rr]);
    }
    float scv = g2[j] * inv, bi = b2[j], be = be2[j];
#pragma unroll
    for (int rr = 0; rr < 16; rr++)
      sm.m.h2s[rg + rr][j] = fmaxf(scv * (a2[rr] + bi) + be, 0.f);
  }
  __syncthreads();

  // layer 3: 64 -> 1 + sigmoid
  if (t < 64) {
    float z = b3[0];
#pragma unroll
    for (int k = 0; k < 64; k++) z = fmaf(sm.m.h2s[t][k], W3[k], z);
    sm.m.ls[t] = 1.f / (1.f + __expf(-z));
  }
  __syncthreads();
  if (t == 0) {
    float s = 0.f;
#pragma unroll
    for (int iL = 0; iL < 64; iL++) s += sm.m.ls[iL];
    atomicAdd(&sums[1], (double)s);
  }
}

// ---- kernel 3: combine ----
__global__ void finalize(const double* __restrict__ sums, float* __restrict__ out) {
  double simmean = sums[0] / ((double)N_IMG * (double)N_IMG);
  double aggmean = sums[1] / (double)N_IMG;
  out[0] = (float)(aggmean * simmean);
}

extern "C" void kernel_launch(void* const* d_in, const int* in_sizes, int n_in,
                              void* d_out, int out_size, void* d_ws, size_t ws_size,
                              hipStream_t stream) {
  const float* f      = (const float*)d_in[0];
  const float* scores = (const float*)d_in[1];
  const float* W1 = (const float*)d_in[2];
  const float* b1 = (const float*)d_in[3];
  const float* g1 = (const float*)d_in[4];
  const float* be1 = (const float*)d_in[5];
  const float* W2 = (const float*)d_in[6];
  const float* b2 = (const float*)d_in[7];
  const float* g2 = (const float*)d_in[8];
  const float* be2 = (const float*)d_in[9];
  const float* W3 = (const float*)d_in[10];
  const float* b3 = (const float*)d_in[11];

  // workspace layout (9.77 MB total)
  char* ws = (char*)d_ws;
  unsigned char* fb8  = (unsigned char*)ws;                  // 9,437,184 B (normalized fp8)
  float* sL           = (float*)(ws + 9437184);              // 36,864 B  (s * C1)
  float* pL           = (float*)(ws + 9474048);              // 36,864 B  (sqrt(s) * C2)
  unsigned short* W1t = (unsigned short*)(ws + 9510912);     // 262,144 B
  double* sums        = (double*)(ws + 9773056);             // 16 B

  convert_prep<<<2432, 256, 0, stream>>>(f, W1, fb8, sL, pL, W1t, sums);
  gram_mlp<<<NMLP + NPAIR, 256, 0, stream>>>(fb8, sL, pL, f, W1t, scores, W1,
                                             b1, g1, be1, W2, b2, g2, be2, W3, b3, sums);
  finalize<<<1, 1, 0, stream>>>(sums, (float*)d_out);
}